// Round 1
// baseline (323.067 us; speedup 1.0000x reference)
//
#include <hip/hip_runtime.h>
#include <hip/hip_bf16.h>
#include <hip/hip_cooperative_groups.h>

namespace cg = cooperative_groups;

// GCNConv: out = A @ (X @ W), fused single cooperative kernel.
// Phase 0: WT[n][k] = bf16(W[k][n])
// Phase 1: Xp = bf16(X @ W) via mfma_f32_16x16x32_bf16, BM=64 tiles (782 tiles)
// Phase 2: out[i,:] = sum_e Xp[colx[e],:], one wave per node, degree-16 fast path

constexpr int D_IN  = 256;
constexpr int D_OUT = 128;
constexpr int BM = 64;
constexpr int BK = 32;
constexpr int LDA = BK + 8;   // padded stride in shorts (40)

using short8  = __attribute__((ext_vector_type(8))) short;
using float4v = __attribute__((ext_vector_type(4))) float;

__device__ inline ushort f2bf(float f) {
    unsigned u = __float_as_uint(f);
    u = (u + 0x7FFFu + ((u >> 16) & 1u)) >> 16;   // RNE
    return (ushort)u;
}

__device__ inline uint pk2bf(float lo, float hi) {
    float2 t; t.x = lo; t.y = hi;
    __hip_bfloat162 b = __float22bfloat162_rn(t);   // v_cvt_pk_bf16_f32
    return *(uint*)&b;
}

__global__ __launch_bounds__(256, 4) void fused_gcn(
    const float* __restrict__ X, const float* __restrict__ W,
    const int* __restrict__ rowp, const int* __restrict__ colx,
    float* __restrict__ out, ushort* __restrict__ WT,
    ushort* __restrict__ Xp, int n)
{
    __shared__ ushort Asl[BM * LDA];      // 5 KB
    __shared__ ushort Bsl[D_OUT * LDA];   // 10 KB
    const int tid  = threadIdx.x;
    const int wave = tid >> 6;
    const int lane = tid & 63;
    const int quad = lane >> 4;
    const int l16  = lane & 15;
    cg::grid_group grid = cg::this_grid();

    // ---- phase 0: W[k][n] fp32 -> WT[n][k] bf16 (32768 elems) ----
    for (int id = blockIdx.x * 256 + tid; id < D_OUT * D_IN; id += gridDim.x * 256) {
        int nn = id >> 8;        // 0..127
        int k  = id & 255;       // 0..255
        WT[nn * 256 + k] = f2bf(W[k * D_OUT + nn]);
    }
    grid.sync();

    // ---- phase 1: Xp = bf16(X @ W), 64-row tiles, grid-stride ----
    const int ntile = (n + BM - 1) / BM;
    for (int tile = blockIdx.x; tile < ntile; tile += gridDim.x) {
        const int row0 = tile * BM;
        float4v acc[8];
#pragma unroll
        for (int t = 0; t < 8; ++t) acc[t] = (float4v){0.f, 0.f, 0.f, 0.f};

        for (int k0 = 0; k0 < D_IN; k0 += BK) {
            // Stage A: 64x32 fp32 -> bf16 LDS. 512 float4, 2 per thread.
#pragma unroll
            for (int i = 0; i < 2; ++i) {
                int idx = i * 256 + tid;   // 0..511
                int r   = idx >> 3;        // 0..63 (8 float4 per 32-float row)
                int c4  = idx & 7;
                int row = row0 + r; if (row > n - 1) row = n - 1;   // clamp
                float4 v = *(const float4*)(X + (size_t)row * D_IN + k0 + c4 * 4);
                uint2 p;
                p.x = pk2bf(v.x, v.y);
                p.y = pk2bf(v.z, v.w);
                *(uint2*)(&Asl[r * LDA + c4 * 4]) = p;   // 8B aligned
            }
            // Stage B: WT rows 0..127, cols k0..k0+31. 512 short8, 2 per thread.
#pragma unroll
            for (int i = 0; i < 2; ++i) {
                int idx = i * 256 + tid;   // 0..511
                int r  = idx >> 2;         // 0..127
                int ch = idx & 3;
                short8 v = *(const short8*)(WT + r * 256 + k0 + ch * 8);
                *(short8*)(&Bsl[r * LDA + ch * 8]) = v;  // 16B aligned
            }
            __syncthreads();

            // A fragment: lane holds A[m = l16][k = quad*8 + j], rows wave*16..+15
            short8 a = *(const short8*)(&Asl[(wave * 16 + l16) * LDA + quad * 8]);
#pragma unroll
            for (int t = 0; t < 8; ++t) {
                // B fragment: lane holds B[k = quad*8 + j][nn = t*16 + l16]
                short8 b = *(const short8*)(&Bsl[(t * 16 + l16) * LDA + quad * 8]);
                acc[t] = __builtin_amdgcn_mfma_f32_16x16x32_bf16(a, b, acc[t], 0, 0, 0);
            }
            __syncthreads();
        }

        // Epilogue: C/D layout col = l16, row = quad*4 + reg
#pragma unroll
        for (int t = 0; t < 8; ++t) {
#pragma unroll
            for (int r = 0; r < 4; ++r) {
                int row = row0 + wave * 16 + quad * 4 + r;
                if (row < n)
                    Xp[(size_t)row * D_OUT + t * 16 + l16] = f2bf(acc[t][r]);
            }
        }
    }
    grid.sync();

    // ---- phase 2: out[i,:] = sum_e Xp[colx[e],:]; one wave per node ----
    const ushort* src = Xp + lane * 2;
    for (int node = blockIdx.x * 4 + wave; node < n; node += gridDim.x * 4) {
        const int e0 = rowp[node];
        const int e1 = rowp[node + 1];
        float s0 = 0.f, s1 = 0.f;
        if (e1 - e0 == 16) {
            int c[16];
#pragma unroll
            for (int i = 0; i < 16; ++i) c[i] = colx[e0 + i];
            uint v[16];
#pragma unroll
            for (int i = 0; i < 16; ++i)
                v[i] = *(const uint*)(src + (size_t)c[i] * D_OUT);  // 16 gathers in flight
#pragma unroll
            for (int i = 0; i < 16; ++i) {
                s0 += __uint_as_float(v[i] << 16);
                s1 += __uint_as_float(v[i] & 0xFFFF0000u);
            }
        } else {
            for (int e = e0; e < e1; ++e) {
                uint v = *(const uint*)(src + (size_t)colx[e] * D_OUT);
                s0 += __uint_as_float(v << 16);
                s1 += __uint_as_float(v & 0xFFFF0000u);
            }
        }
        float2 r2; r2.x = s0; r2.y = s1;
        *(float2*)(out + (size_t)node * D_OUT + lane * 2) = r2;
    }
}

extern "C" void kernel_launch(void* const* d_in, const int* in_sizes, int n_in,
                              void* d_out, int out_size, void* d_ws, size_t ws_size,
                              hipStream_t stream) {
    const float* X    = (const float*)d_in[0];
    const float* W    = (const float*)d_in[1];
    const int*   rowp = (const int*)d_in[2];
    const int*   colx = (const int*)d_in[3];
    float*       out  = (float*)d_out;

    ushort* WT = (ushort*)d_ws;                       // 128*256*2 = 64 KB
    ushort* Xp = (ushort*)((char*)d_ws + 65536);      // n*128*2 = 12.8 MB

    const int n = in_sizes[0] / D_IN;                 // 50000

    // Cooperative grid size: co-resident capacity, capped at 1024 (4/CU target).
    static int grid_blocks = 0;
    if (grid_blocks == 0) {
        int per_cu = 0;
        if (hipOccupancyMaxActiveBlocksPerMultiprocessor(&per_cu, fused_gcn, 256, 0)
                != hipSuccess || per_cu < 1)
            per_cu = 4;   // launch_bounds(256,4) guarantees <=128 VGPR
        int num_cu = 256;
        hipDeviceProp_t prop;
        int dev = 0;
        if (hipGetDevice(&dev) == hipSuccess &&
            hipGetDeviceProperties(&prop, dev) == hipSuccess)
            num_cu = prop.multiProcessorCount;
        long cap = (long)per_cu * num_cu;
        grid_blocks = (int)(cap < 1024 ? cap : 1024);
    }

    void* args[] = {(void*)&X, (void*)&W, (void*)&rowp, (void*)&colx,
                    (void*)&out, (void*)&WT, (void*)&Xp, (void*)&n};
    hipLaunchCooperativeKernel(fused_gcn, dim3(grid_blocks), dim3(256),
                               args, 0, stream);
}

// Round 2
// 154.918 us; speedup vs baseline: 2.0854x; 2.0854x over previous
//
#include <hip/hip_runtime.h>
#include <hip/hip_bf16.h>

// GCNConv: out = A @ (X @ W)
// Stage 0: WT[n][k] = bf16(W[k][n])                        (prep kernel, d_ws)
// Stage 1: Xp = bf16(X @ W)  via bf16 MFMA 16x16x32, BM=64 (782 blocks)
// Stage 2: out[i,:] = sum_e Xp[colx[e],:]  one wave/node, degree-16 fast path

constexpr int D_IN  = 256;
constexpr int D_OUT = 128;
constexpr int BM = 64;
constexpr int BK = 32;
constexpr int LDA = BK + 8;   // padded stride in shorts (40)

using short8  = __attribute__((ext_vector_type(8))) short;
using float4v = __attribute__((ext_vector_type(4))) float;

__device__ inline ushort f2bf(float f) {
    unsigned u = __float_as_uint(f);
    u = (u + 0x7FFFu + ((u >> 16) & 1u)) >> 16;   // RNE
    return (ushort)u;
}

__device__ inline uint pk2bf(float lo, float hi) {
    float2 t; t.x = lo; t.y = hi;
    __hip_bfloat162 b = __float22bfloat162_rn(t);   // v_cvt_pk_bf16_f32
    return *(uint*)&b;
}

// W[k][n] fp32 -> WT[n][k] bf16  (128 rows x 256 cols)
__global__ __launch_bounds__(256) void prep_wt(const float* __restrict__ W,
                                               ushort* __restrict__ WT) {
    int id = blockIdx.x * 256 + threadIdx.x;   // 32768 total
    int nn = id >> 8;        // 0..127
    int k  = id & 255;       // 0..255
    WT[nn * 256 + k] = f2bf(W[k * D_OUT + nn]);
}

__global__ __launch_bounds__(256, 4) void gemm_xw(const float* __restrict__ X,
                                                  const ushort* __restrict__ WT,
                                                  ushort* __restrict__ Xp, int n) {
    __shared__ ushort Asl[BM * LDA];      // 5 KB
    __shared__ ushort Bsl[D_OUT * LDA];   // 10 KB
    const int tid  = threadIdx.x;
    const int wave = tid >> 6;
    const int lane = tid & 63;
    const int quad = lane >> 4;
    const int l16  = lane & 15;
    const int row0 = blockIdx.x * BM;

    float4v acc[8];
#pragma unroll
    for (int t = 0; t < 8; ++t) acc[t] = (float4v){0.f, 0.f, 0.f, 0.f};

    for (int k0 = 0; k0 < D_IN; k0 += BK) {
        // Stage A: 64x32 fp32 -> bf16 LDS. 512 float4, 2 per thread.
#pragma unroll
        for (int i = 0; i < 2; ++i) {
            int idx = i * 256 + tid;   // 0..511
            int r   = idx >> 3;        // 0..63 (8 float4 per 32-float row)
            int c4  = idx & 7;
            int row = row0 + r; if (row > n - 1) row = n - 1;   // clamp, no branch
            float4 v = *(const float4*)(X + (size_t)row * D_IN + k0 + c4 * 4);
            uint2 p;
            p.x = pk2bf(v.x, v.y);
            p.y = pk2bf(v.z, v.w);
            *(uint2*)(&Asl[r * LDA + c4 * 4]) = p;   // 8B aligned (80r + 8c4)
        }
        // Stage B: WT rows 0..127, cols k0..k0+31. 512 short8 chunks, 2 per thread.
#pragma unroll
        for (int i = 0; i < 2; ++i) {
            int idx = i * 256 + tid;   // 0..511
            int r  = idx >> 2;         // 0..127
            int ch = idx & 3;
            short8 v = *(const short8*)(WT + r * 256 + k0 + ch * 8);
            *(short8*)(&Bsl[r * LDA + ch * 8]) = v;  // 16B aligned (80r + 16ch)
        }
        __syncthreads();

        // A fragment: lane holds A[m = l16][k = quad*8 + j], rows wave*16..+15
        short8 a = *(const short8*)(&Asl[(wave * 16 + l16) * LDA + quad * 8]);
#pragma unroll
        for (int t = 0; t < 8; ++t) {
            // B fragment: lane holds B[k = quad*8 + j][nn = t*16 + l16]
            short8 b = *(const short8*)(&Bsl[(t * 16 + l16) * LDA + quad * 8]);
            acc[t] = __builtin_amdgcn_mfma_f32_16x16x32_bf16(a, b, acc[t], 0, 0, 0);
        }
        __syncthreads();
    }

    // Epilogue: C/D layout col = l16, row = quad*4 + reg. Non-temporal stores:
    // Xp is consumed by the NEXT dispatch; don't pollute L2 during gemm.
#pragma unroll
    for (int t = 0; t < 8; ++t) {
#pragma unroll
        for (int r = 0; r < 4; ++r) {
            int row = row0 + wave * 16 + quad * 4 + r;
            if (row < n)
                __builtin_nontemporal_store(
                    f2bf(acc[t][r]),
                    Xp + (size_t)row * D_OUT + t * 16 + l16);
        }
    }
}

// One wave per node; lane covers 2 of 128 cols (4B bf16x2 per edge, coalesced
// into one 256B line per gather). Degree-16 fast path: 16 gathers in flight.
__global__ __launch_bounds__(256) void spmm_agg(const ushort* __restrict__ Xp,
                                                const int* __restrict__ rowp,
                                                const int* __restrict__ colx,
                                                float* __restrict__ out, int n) {
    const int node = blockIdx.x * 4 + (threadIdx.x >> 6);
    const int lane = threadIdx.x & 63;
    if (node >= n) return;
    const int e0 = rowp[node];
    const int e1 = rowp[node + 1];
    const ushort* src = Xp + lane * 2;
    float s0 = 0.f, s1 = 0.f;
    if (e1 - e0 == 16) {
        int c[16];
#pragma unroll
        for (int i = 0; i < 16; ++i) c[i] = colx[e0 + i];   // wave-uniform -> s_load
        uint v[16];
#pragma unroll
        for (int i = 0; i < 16; ++i)
            v[i] = *(const uint*)(src + (size_t)c[i] * D_OUT);  // 16 gathers in flight
#pragma unroll
        for (int i = 0; i < 16; ++i) {
            s0 += __uint_as_float(v[i] << 16);
            s1 += __uint_as_float(v[i] & 0xFFFF0000u);
        }
    } else {
        for (int e = e0; e < e1; ++e) {
            uint v = *(const uint*)(src + (size_t)colx[e] * D_OUT);
            s0 += __uint_as_float(v << 16);
            s1 += __uint_as_float(v & 0xFFFF0000u);
        }
    }
    // Non-temporal: out is a pure 25.6 MB stream; keep it from evicting the
    // 12.8 MB Xp gather table out of per-XCD L2.
    union { float2 f; double d; } u;
    u.f.x = s0; u.f.y = s1;
    __builtin_nontemporal_store(u.d, (double*)(out + (size_t)node * D_OUT + lane * 2));
}

extern "C" void kernel_launch(void* const* d_in, const int* in_sizes, int n_in,
                              void* d_out, int out_size, void* d_ws, size_t ws_size,
                              hipStream_t stream) {
    const float* X    = (const float*)d_in[0];
    const float* W    = (const float*)d_in[1];
    const int*   rowp = (const int*)d_in[2];
    const int*   colx = (const int*)d_in[3];
    float*       out  = (float*)d_out;

    ushort* WT = (ushort*)d_ws;                       // 128*256*2 = 64 KB
    ushort* Xp = (ushort*)((char*)d_ws + 65536);      // n*128*2 = 12.8 MB

    const int n = in_sizes[0] / D_IN;                 // 50000

    prep_wt<<<dim3(128), dim3(256), 0, stream>>>(W, WT);
    gemm_xw<<<dim3((n + BM - 1) / BM), dim3(256), 0, stream>>>(X, WT, Xp, n);
    spmm_agg<<<dim3((n + 3) / 4), dim3(256), 0, stream>>>(Xp, rowp, colx, out, n);
}

// Round 3
// 146.813 us; speedup vs baseline: 2.2005x; 1.0552x over previous
//
#include <hip/hip_runtime.h>
#include <hip/hip_bf16.h>

// GCNConv: out = A @ (X @ W)
// Stage 0: W_T[n][k] = bf16(W[k][n])                       (prep kernel, d_ws)
// Stage 1: Xp_bf16 = bf16(X @ W)   via bf16 MFMA 16x16x32  (d_ws)
// Stage 2: out[i,:] = sum_{e} Xp[colx[e],:]   fp32 accumulate, degree-16 path

constexpr int D_IN  = 256;
constexpr int D_OUT = 128;
constexpr int BM = 128;
constexpr int BK = 32;
constexpr int LDA = BK + 8;   // padded stride in shorts (40)

using short8  = __attribute__((ext_vector_type(8))) short;
using float4v = __attribute__((ext_vector_type(4))) float;

__device__ inline ushort f2bf(float f) {
    unsigned u = __float_as_uint(f);
    u = (u + 0x7FFFu + ((u >> 16) & 1u)) >> 16;   // RNE
    return (ushort)u;
}

__device__ inline uint pk2bf(float lo, float hi) {
    float2 t; t.x = lo; t.y = hi;
    __hip_bfloat162 b = __float22bfloat162_rn(t);   // v_cvt_pk_bf16_f32
    return *(uint*)&b;
}

// W[k][n] fp32 -> W_T[n][k] bf16  (128 rows x 256 cols)
__global__ __launch_bounds__(256) void prep_wt(const float* __restrict__ W,
                                               ushort* __restrict__ WT) {
    int id = blockIdx.x * 256 + threadIdx.x;   // 32768 total
    int nn = id >> 8;        // 0..127
    int k  = id & 255;       // 0..255
    WT[nn * 256 + k] = f2bf(W[k * D_OUT + nn]);
}

__global__ __launch_bounds__(256) void gemm_xw(const float* __restrict__ X,
                                               const ushort* __restrict__ WT,
                                               ushort* __restrict__ Xp, int n) {
    __shared__ ushort Asl[BM * LDA];     // 10 KB
    __shared__ ushort Bsl[D_OUT * LDA];  // 10 KB
    const int tid  = threadIdx.x;
    const int wave = tid >> 6;
    const int lane = tid & 63;
    const int quad = lane >> 4;
    const int l16  = lane & 15;
    const int row0 = blockIdx.x * BM;

    float4v acc[2][8];
#pragma unroll
    for (int i = 0; i < 2; ++i)
#pragma unroll
        for (int t = 0; t < 8; ++t) acc[i][t] = (float4v){0.f, 0.f, 0.f, 0.f};

    for (int k0 = 0; k0 < D_IN; k0 += BK) {
        // Stage A: 128x32 fp32 -> bf16 LDS. 1024 float4, 4 per thread.
#pragma unroll
        for (int i = 0; i < 4; ++i) {
            int idx = i * 256 + tid;
            int r = idx >> 3;        // 8 float4 per 32-float row
            int c4 = idx & 7;
            int row = row0 + r; if (row > n - 1) row = n - 1;   // clamp, no branch
            float4 v = *(const float4*)(X + (size_t)row * D_IN + k0 + c4 * 4);
            uint2 p;
            p.x = pk2bf(v.x, v.y);
            p.y = pk2bf(v.z, v.w);
            *(uint2*)(&Asl[r * LDA + c4 * 4]) = p;   // 8B aligned (80r + 8c4)
        }
        // Stage B: W_T rows 0..127, k0..k0+31. 512 short8 chunks, 2 per thread.
#pragma unroll
        for (int i = 0; i < 2; ++i) {
            int idx = i * 256 + tid;
            int r  = idx >> 2;       // 4 chunks of 8 shorts per 32-short row
            int ch = idx & 3;
            short8 v = *(const short8*)(WT + r * 256 + k0 + ch * 8);
            *(short8*)(&Bsl[r * LDA + ch * 8]) = v;  // 16B aligned (80r + 16ch)
        }
        __syncthreads();

        // A fragments: lane holds A[m = l16][k = quad*8 + j], rows wave*32 + rt*16
        short8 a0 = *(const short8*)(&Asl[(wave * 32 +      l16) * LDA + quad * 8]);
        short8 a1 = *(const short8*)(&Asl[(wave * 32 + 16 + l16) * LDA + quad * 8]);
#pragma unroll
        for (int t = 0; t < 8; ++t) {
            // B fragment: lane holds B[k = quad*8 + j][nn = t*16 + l16]
            short8 b = *(const short8*)(&Bsl[(t * 16 + l16) * LDA + quad * 8]);
            acc[0][t] = __builtin_amdgcn_mfma_f32_16x16x32_bf16(a0, b, acc[0][t], 0, 0, 0);
            acc[1][t] = __builtin_amdgcn_mfma_f32_16x16x32_bf16(a1, b, acc[1][t], 0, 0, 0);
        }
        __syncthreads();
    }

    // Epilogue: C/D layout col = l16, row = quad*4 + reg. Plain stores: Xp is
    // re-read 16x by the next dispatch -- keep it resident in L2 (nt here
    // regressed round 2 by evicting it).
#pragma unroll
    for (int rt = 0; rt < 2; ++rt) {
#pragma unroll
        for (int t = 0; t < 8; ++t) {
#pragma unroll
            for (int r = 0; r < 4; ++r) {
                int row = row0 + wave * 32 + rt * 16 + quad * 4 + r;
                if (row < n)
                    Xp[(size_t)row * D_OUT + t * 16 + l16] = f2bf(acc[rt][t][r]);
            }
        }
    }
}

// One wave per node; lane covers 2 of 128 cols (4B bf16x2 per edge, coalesced).
// Degree-16 fast path: 16 index loads, then 16 gathers all in flight.
__global__ __launch_bounds__(256) void spmm_agg(const ushort* __restrict__ Xp,
                                                const int* __restrict__ rowp,
                                                const int* __restrict__ colx,
                                                float* __restrict__ out, int n) {
    const int node = blockIdx.x * 4 + (threadIdx.x >> 6);
    const int lane = threadIdx.x & 63;
    if (node >= n) return;
    const int e0 = rowp[node];
    const int e1 = rowp[node + 1];
    const ushort* src = Xp + lane * 2;
    float s0 = 0.f, s1 = 0.f;
    if (e1 - e0 == 16) {
        int c[16];
#pragma unroll
        for (int i = 0; i < 16; ++i) c[i] = colx[e0 + i];   // wave-uniform -> s_load
        uint v[16];
#pragma unroll
        for (int i = 0; i < 16; ++i)
            v[i] = *(const uint*)(src + (size_t)c[i] * D_OUT);  // 16 gathers in flight
#pragma unroll
        for (int i = 0; i < 16; ++i) {
            s0 += __uint_as_float(v[i] << 16);
            s1 += __uint_as_float(v[i] & 0xFFFF0000u);
        }
    } else {
        for (int e = e0; e < e1; ++e) {
            uint v = *(const uint*)(src + (size_t)colx[e] * D_OUT);
            s0 += __uint_as_float(v << 16);
            s1 += __uint_as_float(v & 0xFFFF0000u);
        }
    }
    // Non-temporal: out is write-once-never-read (25.6 MB stream); keep it from
    // evicting the 12.8 MB Xp gather working set out of per-XCD L2.
    union { float2 f; double d; } u;
    u.f.x = s0; u.f.y = s1;
    __builtin_nontemporal_store(u.d, (double*)(out + (size_t)node * D_OUT + lane * 2));
}

extern "C" void kernel_launch(void* const* d_in, const int* in_sizes, int n_in,
                              void* d_out, int out_size, void* d_ws, size_t ws_size,
                              hipStream_t stream) {
    const float* X    = (const float*)d_in[0];
    const float* W    = (const float*)d_in[1];
    const int*   rowp = (const int*)d_in[2];
    const int*   colx = (const int*)d_in[3];
    float*       out  = (float*)d_out;

    ushort* WT = (ushort*)d_ws;                       // 128*256*2 = 64 KB
    ushort* Xp = (ushort*)((char*)d_ws + 65536);      // n*128*2 = 12.8 MB

    const int n = in_sizes[0] / D_IN;                 // 50000

    prep_wt<<<dim3(128), dim3(256), 0, stream>>>(W, WT);
    gemm_xw<<<dim3((n + BM - 1) / BM), dim3(256), 0, stream>>>(X, WT, Xp, n);
    spmm_agg<<<dim3((n + 3) / 4), dim3(256), 0, stream>>>(Xp, rowp, colx, out, n);
}

// Round 4
// 146.315 us; speedup vs baseline: 2.2080x; 1.0034x over previous
//
#include <hip/hip_runtime.h>
#include <hip/hip_bf16.h>

// GCNConv: out = A @ (X @ W)
// Stage 0: WT[n][k] = bf16(W[k][n])                         (prep kernel, d_ws)
// Stage 1: Xp = bf16(X @ W) via MFMA 16x16x32.  B (=WT) staged ONCE in LDS for
//          all 256 k; A fragments loaded global->reg; K-loop has NO barriers.
// Stage 2: out[i,:] = sum_e Xp[colx[e],:]  one wave/node, degree-16 fast path

constexpr int D_IN  = 256;
constexpr int D_OUT = 128;
constexpr int BM  = 128;
constexpr int BK  = 32;
constexpr int LDB = 296;  // shorts/row: 592 B = 16B-aligned, 20-dword bank shift
                          // -> ds_read_b128 across 16 rows is conflict-free

using short8  = __attribute__((ext_vector_type(8))) short;
using float4v = __attribute__((ext_vector_type(4))) float;

__device__ inline ushort f2bf(float f) {
    unsigned u = __float_as_uint(f);
    u = (u + 0x7FFFu + ((u >> 16) & 1u)) >> 16;   // RNE
    return (ushort)u;
}

__device__ inline uint pk2bf(float lo, float hi) {
    float2 t; t.x = lo; t.y = hi;
    __hip_bfloat162 b = __float22bfloat162_rn(t);   // v_cvt_pk_bf16_f32
    return *(uint*)&b;
}

// W[k][n] fp32 -> WT[n][k] bf16  (128 rows x 256 cols)
__global__ __launch_bounds__(256) void prep_wt(const float* __restrict__ W,
                                               ushort* __restrict__ WT) {
    int id = blockIdx.x * 256 + threadIdx.x;   // 32768 total
    int nn = id >> 8;        // 0..127
    int k  = id & 255;       // 0..255
    WT[nn * 256 + k] = f2bf(W[k * D_OUT + nn]);
}

__global__ __launch_bounds__(256, 2) void gemm_xw(const float* __restrict__ X,
                                                  const ushort* __restrict__ WT,
                                                  ushort* __restrict__ Xp, int n) {
    __shared__ ushort Bs[D_OUT * LDB];   // 128 x 296 shorts = 74 KB -> 2 blk/CU
    const int tid  = threadIdx.x;
    const int wave = tid >> 6;
    const int lane = tid & 63;
    const int quad = lane >> 4;
    const int l16  = lane & 15;
    const int row0 = blockIdx.x * BM;

    // ---- stage ALL of B once: WT[128][256] -> Bs[128][LDB] ----
#pragma unroll
    for (int i = 0; i < 16; ++i) {
        int idx = i * 256 + tid;       // 0..4095 short8 chunks
        int r   = idx >> 5;            // row 0..127
        int ch  = idx & 31;            // chunk 0..31
        short8 v = *(const short8*)(WT + r * 256 + ch * 8);
        *(short8*)(&Bs[r * LDB + ch * 8]) = v;   // 16B aligned (592r + 16ch)
    }
    __syncthreads();                   // the ONLY barrier in this kernel

    // A rows owned by this lane (clamped; epilogue guards real writes)
    int r0 = row0 + wave * 32 + l16;      if (r0 > n - 1) r0 = n - 1;
    int r1 = row0 + wave * 32 + 16 + l16; if (r1 > n - 1) r1 = n - 1;
    const float* xr0 = X + (size_t)r0 * D_IN + quad * 8;
    const float* xr1 = X + (size_t)r1 * D_IN + quad * 8;

    float4v acc[2][8];
#pragma unroll
    for (int i = 0; i < 2; ++i)
#pragma unroll
        for (int t = 0; t < 8; ++t) acc[i][t] = (float4v){0.f, 0.f, 0.f, 0.f};

    // Barrier-free K-loop: per step, A-frags come straight from global memory
    // (8 contiguous floats per lane per frag); B-frags from resident LDS.
#pragma unroll
    for (int k0 = 0; k0 < D_IN; k0 += BK) {
        float4 u0 = *(const float4*)(xr0 + k0);
        float4 u1 = *(const float4*)(xr0 + k0 + 4);
        float4 w0 = *(const float4*)(xr1 + k0);
        float4 w1 = *(const float4*)(xr1 + k0 + 4);
        union { short8 s; uint u[4]; } A0, A1;
        A0.u[0] = pk2bf(u0.x, u0.y);  A0.u[1] = pk2bf(u0.z, u0.w);
        A0.u[2] = pk2bf(u1.x, u1.y);  A0.u[3] = pk2bf(u1.z, u1.w);
        A1.u[0] = pk2bf(w0.x, w0.y);  A1.u[1] = pk2bf(w0.z, w0.w);
        A1.u[2] = pk2bf(w1.x, w1.y);  A1.u[3] = pk2bf(w1.z, w1.w);
#pragma unroll
        for (int t = 0; t < 8; ++t) {
            // B fragment: lane holds B[k = k0 + quad*8 + j][nn = t*16 + l16]
            short8 b = *(const short8*)(&Bs[(t * 16 + l16) * LDB + k0 + quad * 8]);
            acc[0][t] = __builtin_amdgcn_mfma_f32_16x16x32_bf16(A0.s, b, acc[0][t], 0, 0, 0);
            acc[1][t] = __builtin_amdgcn_mfma_f32_16x16x32_bf16(A1.s, b, acc[1][t], 0, 0, 0);
        }
    }

    // Epilogue: C/D layout col = l16, row = quad*4 + reg. Plain stores: Xp is
    // re-read 16x by the next dispatch -- keep it resident in L2.
#pragma unroll
    for (int rt = 0; rt < 2; ++rt) {
#pragma unroll
        for (int t = 0; t < 8; ++t) {
#pragma unroll
            for (int r = 0; r < 4; ++r) {
                int row = row0 + wave * 32 + rt * 16 + quad * 4 + r;
                if (row < n)
                    Xp[(size_t)row * D_OUT + t * 16 + l16] = f2bf(acc[rt][t][r]);
            }
        }
    }
}

// One wave per node; lane covers 2 of 128 cols (4B bf16x2 per edge, coalesced).
// Degree-16 fast path: 16 index loads, then 16 gathers all in flight.
__global__ __launch_bounds__(256) void spmm_agg(const ushort* __restrict__ Xp,
                                                const int* __restrict__ rowp,
                                                const int* __restrict__ colx,
                                                float* __restrict__ out, int n) {
    const int node = blockIdx.x * 4 + (threadIdx.x >> 6);
    const int lane = threadIdx.x & 63;
    if (node >= n) return;
    const int e0 = rowp[node];
    const int e1 = rowp[node + 1];
    const ushort* src = Xp + lane * 2;
    float s0 = 0.f, s1 = 0.f;
    if (e1 - e0 == 16) {
        int c[16];
#pragma unroll
        for (int i = 0; i < 16; ++i) c[i] = colx[e0 + i];   // wave-uniform -> s_load
        uint v[16];
#pragma unroll
        for (int i = 0; i < 16; ++i)
            v[i] = *(const uint*)(src + (size_t)c[i] * D_OUT);  // 16 gathers in flight
#pragma unroll
        for (int i = 0; i < 16; ++i) {
            s0 += __uint_as_float(v[i] << 16);
            s1 += __uint_as_float(v[i] & 0xFFFF0000u);
        }
    } else {
        for (int e = e0; e < e1; ++e) {
            uint v = *(const uint*)(src + (size_t)colx[e] * D_OUT);
            s0 += __uint_as_float(v << 16);
            s1 += __uint_as_float(v & 0xFFFF0000u);
        }
    }
    // Non-temporal: out is write-once-never-read (25.6 MB stream); keep it from
    // evicting the 12.8 MB Xp gather working set out of per-XCD L2.
    union { float2 f; double d; } u;
    u.f.x = s0; u.f.y = s1;
    __builtin_nontemporal_store(u.d, (double*)(out + (size_t)node * D_OUT + lane * 2));
}

extern "C" void kernel_launch(void* const* d_in, const int* in_sizes, int n_in,
                              void* d_out, int out_size, void* d_ws, size_t ws_size,
                              hipStream_t stream) {
    const float* X    = (const float*)d_in[0];
    const float* W    = (const float*)d_in[1];
    const int*   rowp = (const int*)d_in[2];
    const int*   colx = (const int*)d_in[3];
    float*       out  = (float*)d_out;

    ushort* WT = (ushort*)d_ws;                       // 128*256*2 = 64 KB
    ushort* Xp = (ushort*)((char*)d_ws + 65536);      // n*128*2 = 12.8 MB

    const int n = in_sizes[0] / D_IN;                 // 50000

    prep_wt<<<dim3(128), dim3(256), 0, stream>>>(W, WT);
    gemm_xw<<<dim3((n + BM - 1) / BM), dim3(256), 0, stream>>>(X, WT, Xp, n);
    spmm_agg<<<dim3((n + 3) / 4), dim3(256), 0, stream>>>(Xp, rowp, colx, out, n);
}